// Round 4
// baseline (138.519 us; speedup 1.0000x reference)
//
#include <hip/hip_runtime.h>
#include <cstdint>

#define SEQ_LEN 2048
#define DIM 1024
#define NHEAD 16
#define DHEAD 64
#define QKV_LD (3 * DIM)

typedef unsigned short u16;
typedef short bf16x8 __attribute__((ext_vector_type(8)));
typedef float f32x4 __attribute__((ext_vector_type(4)));

__device__ __forceinline__ u16 f2bf(float f) {
    union { float f; unsigned u; } v;
    v.f = f;
    unsigned r = v.u + 0x7fff + ((v.u >> 16) & 1);  // RNE
    return (u16)(r >> 16);
}

// async global -> LDS, 16 B per lane (global_load_lds_dwordx4)
__device__ __forceinline__ void load_lds16(const void* g, void* l) {
    __builtin_amdgcn_global_load_lds(
        (const __attribute__((address_space(1))) void*)g,
        (__attribute__((address_space(3))) void*)l, 16, 0, 0);
}

// ---------------------------------------------------------------------------
// Fused prep: [0,2048) cast x -> bf16 ; [2048,2816) transpose Wqkv (64x64) ;
// [2816,3072) transpose Wout (64x64). Branch is block-uniform.
// 64x64 fp32 tile: float4 loads (16B/lane), uint4 bf16 stores (16B/lane).
// ---------------------------------------------------------------------------
__device__ __forceinline__ void transpose_tile64(const float* __restrict__ W,
                                                 u16* __restrict__ Wt, int K, int N,
                                                 int bx, int by, int t,
                                                 float (*tile)[65]) {
    const int n0 = bx * 64, k0 = by * 64;
    const int c4 = (t & 15) * 4;
    const int r0 = t >> 4;  // 16 rows per pass
#pragma unroll
    for (int i = 0; i < 4; ++i) {
        const int r = i * 16 + r0;
        const float4 v =
            *reinterpret_cast<const float4*>(&W[(size_t)(k0 + r) * N + n0 + c4]);
        tile[r][c4] = v.x;
        tile[r][c4 + 1] = v.y;
        tile[r][c4 + 2] = v.z;
        tile[r][c4 + 3] = v.w;
    }
    __syncthreads();
#pragma unroll
    for (int p = 0; p < 2; ++p) {
        const int idx = p * 256 + t;
        const int n = idx >> 3;       // 0..63
        const int ck = idx & 7;       // k chunk of 8
        unsigned o[4];
#pragma unroll
        for (int jj = 0; jj < 4; ++jj) {
            const u16 lo = f2bf(tile[ck * 8 + jj * 2][n]);
            const u16 hi = f2bf(tile[ck * 8 + jj * 2 + 1][n]);
            o[jj] = (unsigned)lo | ((unsigned)hi << 16);
        }
        *reinterpret_cast<uint4*>(&Wt[(size_t)(n0 + n) * K + k0 + ck * 8]) =
            make_uint4(o[0], o[1], o[2], o[3]);
    }
}

__global__ __launch_bounds__(256) void prep_k(const float* __restrict__ x,
                                              const float* __restrict__ Wqkv,
                                              const float* __restrict__ Wout,
                                              u16* __restrict__ xb,
                                              u16* __restrict__ Wqkvt,
                                              u16* __restrict__ Woutt) {
    __shared__ float tile[64][65];
    const int b = blockIdx.x;
    const int t = threadIdx.x;
    if (b < 2048) {  // cast x
        const int i = b * 256 + t;
        const float4 v = reinterpret_cast<const float4*>(x)[i];
        const unsigned p0 = (unsigned)f2bf(v.x) | ((unsigned)f2bf(v.y) << 16);
        const unsigned p1 = (unsigned)f2bf(v.z) | ((unsigned)f2bf(v.w) << 16);
        reinterpret_cast<uint2*>(xb)[i] = make_uint2(p0, p1);
    } else if (b < 2816) {  // Wqkv [1024,3072] -> [3072,1024]: 48 x 16 tiles
        const int b2 = b - 2048;
        transpose_tile64(Wqkv, Wqkvt, DIM, QKV_LD, b2 % 48, b2 / 48, t, tile);
    } else {  // Wout [1024,1024] -> transposed: 16 x 16 tiles
        const int b3 = b - 2816;
        transpose_tile64(Wout, Woutt, DIM, DIM, b3 & 15, b3 >> 4, t, tile);
    }
}

// ---------------------------------------------------------------------------
// bf16 MFMA GEMM: C = A[M,K] @ Bt[N,K]^T. Tile BM x BN x BK, dbuf DMA LDS,
// one barrier/K-iter. 4 waves: 2(m) x 2(n).
// MODE 0 (QKV producer): writes Q natural [s][1024]; K d-group-swizzled
//   [s][1024] (groups of 8 d XORed by s&7); V transposed [hd][2048] with
//   psi-interleaved kv 4-blocks (PV A-fragment k-order) and 8-groups XORed
//   by d&7 (attention consumes both fragments directly, DMA-stageable).
// MODE 1: fp32 output + bias.
// ---------------------------------------------------------------------------
template <int MODE, int BM, int BN, int BK>
__global__ __launch_bounds__(256) void gemm_bf16(const u16* __restrict__ A,
                                                 const u16* __restrict__ Bt,
                                                 const float* __restrict__ bias,
                                                 void* __restrict__ Cout,
                                                 u16* __restrict__ kout,
                                                 u16* __restrict__ vout,
                                                 int M, int N, int K) {
    constexpr int AI = BM / 32;
    constexpr int BJ = BN / 32;
    constexpr int ASZ = BM * BK;
    constexpr int BSZ = BN * BK;
    __shared__ u16 As[2 * ASZ];
    __shared__ u16 Bs[2 * BSZ];

    const int t = threadIdx.x;
    const int lane = t & 63;
    const int quad = lane >> 4;
    const int l15 = lane & 15;
    const int w = t >> 6;
    const int wm = (w & 1) * (BM / 2);
    const int wn = (w >> 1) * (BN / 2);
    const int m0 = blockIdx.y * BM;
    const int n0 = blockIdx.x * BN;
    const int sr = t >> 2;
    const int sc = (t & 3) << 3;

    const u16* Ab = A + (size_t)(m0 + sr) * K + sc;
    const u16* Bb = Bt + (size_t)(n0 + sr) * K + sc;

    auto stage = [&](int buf, int k0) {
#pragma unroll
        for (int kc = 0; kc < BK / 32; ++kc) {
#pragma unroll
            for (int c = 0; c < BM / 64; ++c)
                load_lds16(Ab + (size_t)(c * 64) * K + k0 + kc * 32,
                           &As[buf * ASZ + kc * BM * 32 + c * 2048 + t * 8]);
#pragma unroll
            for (int c = 0; c < BN / 64; ++c)
                load_lds16(Bb + (size_t)(c * 64) * K + k0 + kc * 32,
                           &Bs[buf * BSZ + kc * BN * 32 + c * 2048 + t * 8]);
        }
    };

    stage(0, 0);
    f32x4 acc[AI][BJ] = {};

    const int niter = K / BK;
    for (int it = 0; it < niter; ++it) {
        const int cur = it & 1, nxt = cur ^ 1;
        __syncthreads();
        if (it + 1 < niter) stage(nxt, (it + 1) * BK);
#pragma unroll
        for (int kc = 0; kc < BK / 32; ++kc) {
            bf16x8 af[AI], bfr[BJ];
#pragma unroll
            for (int i = 0; i < AI; ++i)
                af[i] = *reinterpret_cast<const bf16x8*>(
                    &As[cur * ASZ + kc * BM * 32 + (wm + i * 16 + l15) * 32 + quad * 8]);
#pragma unroll
            for (int j = 0; j < BJ; ++j)
                bfr[j] = *reinterpret_cast<const bf16x8*>(
                    &Bs[cur * BSZ + kc * BN * 32 + (wn + j * 16 + l15) * 32 + quad * 8]);
#pragma unroll
            for (int i = 0; i < AI; ++i)
#pragma unroll
                for (int j = 0; j < BJ; ++j)
                    acc[i][j] =
                        __builtin_amdgcn_mfma_f32_16x16x32_bf16(af[i], bfr[j], acc[i][j], 0, 0, 0);
        }
    }

    if constexpr (MODE == 1) {
#pragma unroll
        for (int j = 0; j < BJ; ++j) {
            const int col = n0 + wn + j * 16 + l15;
            const float bv = bias[col];
#pragma unroll
            for (int i = 0; i < AI; ++i) {
                const int row = m0 + wm + i * 16 + quad * 4;
#pragma unroll
                for (int r = 0; r < 4; ++r)
                    ((float*)Cout)[(size_t)(row + r) * N + col] = acc[i][j][r] + bv;
            }
        }
    } else {
        const int region = n0 >> 10;  // 0=Q, 1=K, 2=V (BN=64 keeps blocks uniform)
        if (region == 0) {
#pragma unroll
            for (int j = 0; j < BJ; ++j) {
                const int col = n0 + wn + j * 16 + l15;
#pragma unroll
                for (int i = 0; i < AI; ++i) {
                    const int row = m0 + wm + i * 16 + quad * 4;
#pragma unroll
                    for (int r = 0; r < 4; ++r)
                        ((u16*)Cout)[(size_t)(row + r) * DIM + col] = f2bf(acc[i][j][r]);
                }
            }
        } else if (region == 1) {  // K: d-groups swizzled by s&7
#pragma unroll
            for (int j = 0; j < BJ; ++j) {
                const int hd = n0 + wn + j * 16 + l15 - 1024;
                const int d = hd & 63, hb = hd & ~63;
#pragma unroll
                for (int i = 0; i < AI; ++i) {
                    const int row = m0 + wm + i * 16 + quad * 4;
#pragma unroll
                    for (int r = 0; r < 4; ++r) {
                        const int s = row + r;
                        const int pos = hb + ((((d >> 3) ^ (s & 7)) << 3) | (d & 7));
                        kout[(size_t)s * DIM + pos] = f2bf(acc[i][j][r]);
                    }
                }
            }
        } else {  // V^T: [hd][s], psi-interleaved 4-blocks, groups ^ (d&7)
#pragma unroll
            for (int j = 0; j < BJ; ++j) {
                const int hd = n0 + wn + j * 16 + l15 - 2048;
#pragma unroll
                for (int i = 0; i < AI; ++i) {
                    const int srow = m0 + wm + i * 16 + quad * 4;
                    const unsigned p0 = (unsigned)f2bf(acc[i][j][0]) |
                                        ((unsigned)f2bf(acc[i][j][1]) << 16);
                    const unsigned p1 = (unsigned)f2bf(acc[i][j][2]) |
                                        ((unsigned)f2bf(acc[i][j][3]) << 16);
                    // psi: logical 8-group lg = (wk half)*4 + kv4-block&3;
                    // 8B half within group = kv bit 4. Then XOR lg by d&7.
                    const int s6 = srow & 63;
                    const int lg = ((s6 >> 5) << 2) | ((s6 >> 2) & 3);
                    const int half = (s6 >> 4) & 1;
                    const int pos =
                        (srow & ~63) + ((lg ^ (hd & 7)) << 3) + (half << 2);
                    *reinterpret_cast<uint2*>(&vout[(size_t)hd * SEQ_LEN + pos]) =
                        make_uint2(p0, p1);
                }
            }
        }
    }
}

// ---------------------------------------------------------------------------
// MFMA causal flash attention, no-max softmax, ALL staging via DMA.
// SWAPPED QK^T: S^T = mfma(K, Q) puts lane l15 = q, rows = kv, so the
// exp2'd tile IS the PV A-fragment under the kv-permutation psi that the
// producer bakes into V^T. P never touches LDS (no transpose, no spill).
// Block = 64 q-rows x 1 head (512 blocks). LPT pairing: first 256 dispatched
// blocks take qt=31..16 (heavy), second 256 take qt=0..15 -> each CU's block
// pair sums to exactly 33 kv-tiles.
// 4 waves = 2(q-half of 32) x 2(kv-half of 32); K/V^T double-buffered, one
// barrier per kv-tile, DMA prefetch right after barrier. s_setprio(1) wraps
// the MFMA clusters (T5: 2 blocks/CU at different phases -> scheduler can
// prefer the MFMA wave while the partner block runs softmax VALU).
// Epilogue combines the two kv-half waves via LDS overlay. LDS 40 KB.
// ---------------------------------------------------------------------------
__global__ __launch_bounds__(256) void attn_mfma(const u16* __restrict__ Qb,
                                                 const u16* __restrict__ Kb,
                                                 const u16* __restrict__ Vg,
                                                 u16* __restrict__ O) {
    __shared__ u16 SM[4096 + 8192 + 8192];  // 40960 B
    u16* Qs = SM;                // [64 q][64 d]
    u16* Ks = SM + 4096;         // [2 buf][64 kv][64 d], d-groups ^ (s&7)
    u16* Vs = SM + 4096 + 8192;  // [2 buf][64 d][64 kv], psi + groups ^ (d&7)
    // epilogue overlays (main-loop LDS dead by then):
    float* OredF = (float*)SM;           // [64 q][68] fp32 (17408 B)
    float* Lr = (float*)(SM + 8704);     // [2 wk][64 q] fp32 (512 B @ 17408)

    const int b = blockIdx.x;
    const int hb = b >> 4;
    // LPT pairing: CU gets blocks b and b+256 -> qt pair (31-hb, hb) sums 33
    const int qt = (hb < 16) ? (31 - hb) : (hb - 16);
    const int h = b & 15;
    const int q0 = qt * 64;

    const int t = threadIdx.x;
    const int lane = t & 63;
    const int quad = lane >> 4;
    const int l15 = lane & 15;
    const int w = t >> 6;
    const int wq = w >> 1;  // q half (32 rows)
    const int wk = w & 1;   // kv half (32 cols)

    const int drow = t >> 3;       // DMA: row within 32-row group
    const int doff = (t & 7) * 8;  // DMA: 16B lane offset (u16 units)

    auto stageK = [&](int buf, int j0) {
#pragma unroll
        for (int c = 0; c < 2; ++c)
            load_lds16(Kb + (size_t)(j0 + c * 32 + drow) * DIM + h * DHEAD + doff,
                       &Ks[buf * 4096 + c * 2048 + t * 8]);
    };
    auto stageV = [&](int buf, int j0) {
#pragma unroll
        for (int c = 0; c < 2; ++c)
            load_lds16(Vg + (size_t)(h * DHEAD + c * 32 + drow) * SEQ_LEN + j0 + doff,
                       &Vs[buf * 4096 + c * 2048 + t * 8]);
    };

    // ---- prologue: stage Q, K0, V0 ----
#pragma unroll
    for (int c = 0; c < 2; ++c)
        load_lds16(Qb + (size_t)(q0 + c * 32 + drow) * DIM + h * DHEAD + doff,
                   &Qs[c * 2048 + t * 8]);
    stageK(0, 0);
    stageV(0, 0);
    __syncthreads();  // all prologue DMA drained

    // Q as B-fragment: lane l15 = q, quad = d-group (same map as A-fragment)
    bf16x8 qf[2][2];
#pragma unroll
    for (int qq = 0; qq < 2; ++qq)
#pragma unroll
        for (int dc = 0; dc < 2; ++dc)
            qf[qq][dc] = *reinterpret_cast<const bf16x8*>(
                &Qs[(wq * 32 + qq * 16 + l15) * 64 + dc * 32 + quad * 8]);

    f32x4 oacc[2][4] = {};
    float lsum[2] = {};
    constexpr float SCL = 0.18033688f;  // (1/8)*log2(e)

    for (int jt = 0; jt <= qt; ++jt) {
        const int cur = jt & 1, nxt = cur ^ 1;
        if (jt > 0) __syncthreads();  // buf[cur] DMA drained; buf[nxt] readers done
        if (jt < qt) {                // prefetch next tile right after barrier
            stageK(nxt, (jt + 1) * 64);
            stageV(nxt, (jt + 1) * 64);
        }

        // ---- S^T = K @ Q^T (wave: 32 kv x 32 q), lane l15 = q ----
        f32x4 sacc[2][2] = {};  // [qq][nn kv-tile]
        __builtin_amdgcn_s_setprio(1);
#pragma unroll
        for (int nn = 0; nn < 2; ++nn)
#pragma unroll
            for (int dc = 0; dc < 2; ++dc) {
                const bf16x8 kf = *reinterpret_cast<const bf16x8*>(
                    &Ks[cur * 4096 + (wk * 32 + nn * 16 + l15) * 64 +
                        (((dc * 4 + quad) ^ (l15 & 7)) << 3)]);
#pragma unroll
                for (int qq = 0; qq < 2; ++qq)
                    sacc[qq][nn] =
                        __builtin_amdgcn_mfma_f32_16x16x32_bf16(kf, qf[qq][dc], sacc[qq][nn], 0, 0, 0);
            }
        __builtin_amdgcn_s_setprio(0);

        // ---- no-max softmax fully in-register; lane holds kv slots ----
        // S^T rows (kv) at quad*4+r per nn-tile == PV A-fragment psi order.
        const bool diag = (jt == qt);
        bf16x8 pfr[2];
#pragma unroll
        for (int qq = 0; qq < 2; ++qq) {
            const int qrow = wq * 32 + qq * 16 + l15;
#pragma unroll
            for (int nn = 0; nn < 2; ++nn)
#pragma unroll
                for (int r = 0; r < 4; ++r) {
                    float p = sacc[qq][nn][r] * SCL;
                    if (diag && (wk * 32 + nn * 16 + quad * 4 + r > qrow)) p = -1e30f;
                    p = exp2f(p);
                    lsum[qq] += p;
                    pfr[qq][nn * 4 + r] = (short)(__float_as_uint(p) >> 16);
                }
        }

        // ---- O += P @ V (wave's 32-kv slice of V^T; psi-matched) ----
        __builtin_amdgcn_s_setprio(1);
#pragma unroll
        for (int nd = 0; nd < 4; ++nd) {
            const bf16x8 vf = *reinterpret_cast<const bf16x8*>(
                &Vs[cur * 4096 + (nd * 16 + l15) * 64 +
                    (((wk * 4 + quad) ^ (l15 & 7)) << 3)]);
#pragma unroll
            for (int qq = 0; qq < 2; ++qq)
                oacc[qq][nd] =
                    __builtin_amdgcn_mfma_f32_16x16x32_bf16(pfr[qq], vf, oacc[qq][nd], 0, 0, 0);
        }
        __builtin_amdgcn_s_setprio(0);
    }

    // ---- epilogue ----
    // lsum lives per-lane at q = l15 (per qq); reduce over quad lanes.
#pragma unroll
    for (int qq = 0; qq < 2; ++qq) {
        lsum[qq] += __shfl_xor(lsum[qq], 16, 64);
        lsum[qq] += __shfl_xor(lsum[qq], 32, 64);
    }
    __syncthreads();  // main-loop LDS dead; overlays safe
    if (quad == 0) {  // publish per-row l partials (both kv halves)
#pragma unroll
        for (int qq = 0; qq < 2; ++qq)
            Lr[wk * 64 + wq * 32 + qq * 16 + l15] = lsum[qq];
    }
    // wk=1 waves publish their kv-half O partials to LDS
    if (wk == 1) {
#pragma unroll
        for (int qq = 0; qq < 2; ++qq)
#pragma unroll
            for (int r = 0; r < 4; ++r) {
                const int rowl = wq * 32 + qq * 16 + quad * 4 + r;
#pragma unroll
                for (int nd = 0; nd < 4; ++nd)
                    OredF[rowl * 68 + nd * 16 + l15] = oacc[qq][nd][r];
            }
    }
    __syncthreads();
    // wk=0 waves combine, normalize (combined l > 0 always), write bf16
    if (wk == 0) {
#pragma unroll
        for (int qq = 0; qq < 2; ++qq)
#pragma unroll
            for (int r = 0; r < 4; ++r) {
                const int rowl = wq * 32 + qq * 16 + quad * 4 + r;
                const float inv = 1.0f / (Lr[rowl] + Lr[64 + rowl]);
                const int row = q0 + rowl;
#pragma unroll
                for (int nd = 0; nd < 4; ++nd)
                    O[(size_t)row * DIM + h * DHEAD + nd * 16 + l15] =
                        f2bf((oacc[qq][nd][r] + OredF[rowl * 68 + nd * 16 + l15]) * inv);
            }
    }
}

// ---------------------------------------------------------------------------
extern "C" void kernel_launch(void* const* d_in, const int* in_sizes, int n_in,
                              void* d_out, int out_size, void* d_ws, size_t ws_size,
                              hipStream_t stream) {
    const float* x = (const float*)d_in[0];     // [2048,1024]
    const float* Wqkv = (const float*)d_in[1];  // [1024,3072]
    const float* Wout = (const float*)d_in[2];  // [1024,1024]
    const float* bias = (const float*)d_in[3];  // [1024]
    float* out = (float*)d_out;

    char* ws = (char*)d_ws;
    u16* xb = (u16*)ws;                     // 4 MB
    u16* Wqkvt = (u16*)(ws + (4u << 20));   // 6 MB  [3072,1024]
    u16* Woutt = (u16*)(ws + (10u << 20));  // 2 MB  [1024,1024]
    u16* Qb = (u16*)(ws + (12u << 20));     // 4 MB  [2048,1024]
    u16* Kb = (u16*)(ws + (16u << 20));     // 4 MB  [2048,1024] swizzled
    u16* Vg = (u16*)(ws + (20u << 20));     // 4 MB  [1024,2048] V^T psi+swz
    u16* Ob = (u16*)(ws + (24u << 20));     // 4 MB  [2048,1024]

    // fused prep: cast x + transpose Wqkv + transpose Wout (64x64 vectorized)
    prep_k<<<dim3(3072), 256, 0, stream>>>(x, Wqkv, Wout, xb, Wqkvt, Woutt);

    // qkv = x @ Wqkv, split-layout epilogue (Q / K-swizzled / V^T-psi)
    // 128x64xBK=64: 768 blocks = 3/CU exactly (grid balance beats tile size
    // here -- 128x128 gave 384 blocks = 1.5 rounds, measured neutral/worse)
    gemm_bf16<0, 128, 64, 64><<<dim3(QKV_LD / 64, SEQ_LEN / 128), 256, 0, stream>>>(
        xb, Wqkvt, nullptr, Qb, Kb, Vg, SEQ_LEN, QKV_LD, DIM);

    // causal attention: 512 blocks, LPT-paired (each CU pair sums 33 tiles)
    attn_mfma<<<dim3(32 * NHEAD), 256, 0, stream>>>(Qb, Kb, Vg, Ob);

    // out = O @ Wout + bias (fp32): 64x64x64 tiles -> 512 blocks
    gemm_bf16<1, 64, 64, 64><<<dim3(DIM / 64, SEQ_LEN / 64), 256, 0, stream>>>(
        Ob, Woutt, bias, out, nullptr, nullptr, SEQ_LEN, DIM, DIM);
}

// Round 5
// 136.546 us; speedup vs baseline: 1.0144x; 1.0144x over previous
//
#include <hip/hip_runtime.h>
#include <cstdint>

#define SEQ_LEN 2048
#define DIM 1024
#define NHEAD 16
#define DHEAD 64
#define QKV_LD (3 * DIM)

typedef unsigned short u16;
typedef short bf16x8 __attribute__((ext_vector_type(8)));
typedef float f32x4 __attribute__((ext_vector_type(4)));

__device__ __forceinline__ u16 f2bf(float f) {
    union { float f; unsigned u; } v;
    v.f = f;
    unsigned r = v.u + 0x7fff + ((v.u >> 16) & 1);  // RNE
    return (u16)(r >> 16);
}

// async global -> LDS, 16 B per lane (global_load_lds_dwordx4)
__device__ __forceinline__ void load_lds16(const void* g, void* l) {
    __builtin_amdgcn_global_load_lds(
        (const __attribute__((address_space(1))) void*)g,
        (__attribute__((address_space(3))) void*)l, 16, 0, 0);
}

// (1/8)*log2(e): folded into Q at QKV-epilogue time so attn softmax is
// exp2-only (S arrives pre-scaled).
#define QSCL 0.18033688f

// ---------------------------------------------------------------------------
// Fused prep: [0,2048) cast x -> bf16 ; [2048,2816) transpose Wqkv (64x64) ;
// [2816,3072) transpose Wout (64x64). Branch is block-uniform.
// 64x64 fp32 tile: float4 loads (16B/lane), uint4 bf16 stores (16B/lane).
// ---------------------------------------------------------------------------
__device__ __forceinline__ void transpose_tile64(const float* __restrict__ W,
                                                 u16* __restrict__ Wt, int K, int N,
                                                 int bx, int by, int t,
                                                 float (*tile)[65]) {
    const int n0 = bx * 64, k0 = by * 64;
    const int c4 = (t & 15) * 4;
    const int r0 = t >> 4;  // 16 rows per pass
#pragma unroll
    for (int i = 0; i < 4; ++i) {
        const int r = i * 16 + r0;
        const float4 v =
            *reinterpret_cast<const float4*>(&W[(size_t)(k0 + r) * N + n0 + c4]);
        tile[r][c4] = v.x;
        tile[r][c4 + 1] = v.y;
        tile[r][c4 + 2] = v.z;
        tile[r][c4 + 3] = v.w;
    }
    __syncthreads();
#pragma unroll
    for (int p = 0; p < 2; ++p) {
        const int idx = p * 256 + t;
        const int n = idx >> 3;       // 0..63
        const int ck = idx & 7;       // k chunk of 8
        unsigned o[4];
#pragma unroll
        for (int jj = 0; jj < 4; ++jj) {
            const u16 lo = f2bf(tile[ck * 8 + jj * 2][n]);
            const u16 hi = f2bf(tile[ck * 8 + jj * 2 + 1][n]);
            o[jj] = (unsigned)lo | ((unsigned)hi << 16);
        }
        *reinterpret_cast<uint4*>(&Wt[(size_t)(n0 + n) * K + k0 + ck * 8]) =
            make_uint4(o[0], o[1], o[2], o[3]);
    }
}

__global__ __launch_bounds__(256) void prep_k(const float* __restrict__ x,
                                              const float* __restrict__ Wqkv,
                                              const float* __restrict__ Wout,
                                              u16* __restrict__ xb,
                                              u16* __restrict__ Wqkvt,
                                              u16* __restrict__ Woutt) {
    __shared__ float tile[64][65];
    const int b = blockIdx.x;
    const int t = threadIdx.x;
    if (b < 2048) {  // cast x
        const int i = b * 256 + t;
        const float4 v = reinterpret_cast<const float4*>(x)[i];
        const unsigned p0 = (unsigned)f2bf(v.x) | ((unsigned)f2bf(v.y) << 16);
        const unsigned p1 = (unsigned)f2bf(v.z) | ((unsigned)f2bf(v.w) << 16);
        reinterpret_cast<uint2*>(xb)[i] = make_uint2(p0, p1);
    } else if (b < 2816) {  // Wqkv [1024,3072] -> [3072,1024]: 48 x 16 tiles
        const int b2 = b - 2048;
        transpose_tile64(Wqkv, Wqkvt, DIM, QKV_LD, b2 % 48, b2 / 48, t, tile);
    } else {  // Wout [1024,1024] -> transposed: 16 x 16 tiles
        const int b3 = b - 2816;
        transpose_tile64(Wout, Woutt, DIM, DIM, b3 & 15, b3 >> 4, t, tile);
    }
}

// ---------------------------------------------------------------------------
// bf16 MFMA GEMM: C = A[M,K] @ Bt[N,K]^T. Tile BM x BN x BK, dbuf DMA LDS,
// one barrier/K-iter. 4 waves: 2(m) x 2(n).
// MODE 0 (QKV producer): writes Q natural [s][1024] PRE-SCALED by QSCL
//   (attn softmax becomes exp2-only); K d-group-swizzled [s][1024] (groups
//   of 8 d XORed by s&7); V transposed [hd][2048] with psi-interleaved kv
//   4-blocks (PV A-fragment k-order) and 8-groups XORed by d&7.
// MODE 1: fp32 output + bias.
// ---------------------------------------------------------------------------
template <int MODE, int BM, int BN, int BK>
__global__ __launch_bounds__(256) void gemm_bf16(const u16* __restrict__ A,
                                                 const u16* __restrict__ Bt,
                                                 const float* __restrict__ bias,
                                                 void* __restrict__ Cout,
                                                 u16* __restrict__ kout,
                                                 u16* __restrict__ vout,
                                                 int M, int N, int K) {
    constexpr int AI = BM / 32;
    constexpr int BJ = BN / 32;
    constexpr int ASZ = BM * BK;
    constexpr int BSZ = BN * BK;
    __shared__ u16 As[2 * ASZ];
    __shared__ u16 Bs[2 * BSZ];

    const int t = threadIdx.x;
    const int lane = t & 63;
    const int quad = lane >> 4;
    const int l15 = lane & 15;
    const int w = t >> 6;
    const int wm = (w & 1) * (BM / 2);
    const int wn = (w >> 1) * (BN / 2);
    const int m0 = blockIdx.y * BM;
    const int n0 = blockIdx.x * BN;
    const int sr = t >> 2;
    const int sc = (t & 3) << 3;

    const u16* Ab = A + (size_t)(m0 + sr) * K + sc;
    const u16* Bb = Bt + (size_t)(n0 + sr) * K + sc;

    auto stage = [&](int buf, int k0) {
#pragma unroll
        for (int kc = 0; kc < BK / 32; ++kc) {
#pragma unroll
            for (int c = 0; c < BM / 64; ++c)
                load_lds16(Ab + (size_t)(c * 64) * K + k0 + kc * 32,
                           &As[buf * ASZ + kc * BM * 32 + c * 2048 + t * 8]);
#pragma unroll
            for (int c = 0; c < BN / 64; ++c)
                load_lds16(Bb + (size_t)(c * 64) * K + k0 + kc * 32,
                           &Bs[buf * BSZ + kc * BN * 32 + c * 2048 + t * 8]);
        }
    };

    stage(0, 0);
    f32x4 acc[AI][BJ] = {};

    const int niter = K / BK;
    for (int it = 0; it < niter; ++it) {
        const int cur = it & 1, nxt = cur ^ 1;
        __syncthreads();
        if (it + 1 < niter) stage(nxt, (it + 1) * BK);
#pragma unroll
        for (int kc = 0; kc < BK / 32; ++kc) {
            bf16x8 af[AI], bfr[BJ];
#pragma unroll
            for (int i = 0; i < AI; ++i)
                af[i] = *reinterpret_cast<const bf16x8*>(
                    &As[cur * ASZ + kc * BM * 32 + (wm + i * 16 + l15) * 32 + quad * 8]);
#pragma unroll
            for (int j = 0; j < BJ; ++j)
                bfr[j] = *reinterpret_cast<const bf16x8*>(
                    &Bs[cur * BSZ + kc * BN * 32 + (wn + j * 16 + l15) * 32 + quad * 8]);
#pragma unroll
            for (int i = 0; i < AI; ++i)
#pragma unroll
                for (int j = 0; j < BJ; ++j)
                    acc[i][j] =
                        __builtin_amdgcn_mfma_f32_16x16x32_bf16(af[i], bfr[j], acc[i][j], 0, 0, 0);
        }
    }

    if constexpr (MODE == 1) {
#pragma unroll
        for (int j = 0; j < BJ; ++j) {
            const int col = n0 + wn + j * 16 + l15;
            const float bv = bias[col];
#pragma unroll
            for (int i = 0; i < AI; ++i) {
                const int row = m0 + wm + i * 16 + quad * 4;
#pragma unroll
                for (int r = 0; r < 4; ++r)
                    ((float*)Cout)[(size_t)(row + r) * N + col] = acc[i][j][r] + bv;
            }
        }
    } else {
        const int region = n0 >> 10;  // 0=Q, 1=K, 2=V (BN=64 keeps blocks uniform)
        if (region == 0) {  // Q: pre-scaled by QSCL (see attn softmax)
#pragma unroll
            for (int j = 0; j < BJ; ++j) {
                const int col = n0 + wn + j * 16 + l15;
#pragma unroll
                for (int i = 0; i < AI; ++i) {
                    const int row = m0 + wm + i * 16 + quad * 4;
#pragma unroll
                    for (int r = 0; r < 4; ++r)
                        ((u16*)Cout)[(size_t)(row + r) * DIM + col] =
                            f2bf(acc[i][j][r] * QSCL);
                }
            }
        } else if (region == 1) {  // K: d-groups swizzled by s&7
#pragma unroll
            for (int j = 0; j < BJ; ++j) {
                const int hd = n0 + wn + j * 16 + l15 - 1024;
                const int d = hd & 63, hb = hd & ~63;
#pragma unroll
                for (int i = 0; i < AI; ++i) {
                    const int row = m0 + wm + i * 16 + quad * 4;
#pragma unroll
                    for (int r = 0; r < 4; ++r) {
                        const int s = row + r;
                        const int pos = hb + ((((d >> 3) ^ (s & 7)) << 3) | (d & 7));
                        kout[(size_t)s * DIM + pos] = f2bf(acc[i][j][r]);
                    }
                }
            }
        } else {  // V^T: [hd][s], psi-interleaved 4-blocks, groups ^ (d&7)
#pragma unroll
            for (int j = 0; j < BJ; ++j) {
                const int hd = n0 + wn + j * 16 + l15 - 2048;
#pragma unroll
                for (int i = 0; i < AI; ++i) {
                    const int srow = m0 + wm + i * 16 + quad * 4;
                    const unsigned p0 = (unsigned)f2bf(acc[i][j][0]) |
                                        ((unsigned)f2bf(acc[i][j][1]) << 16);
                    const unsigned p1 = (unsigned)f2bf(acc[i][j][2]) |
                                        ((unsigned)f2bf(acc[i][j][3]) << 16);
                    // psi: logical 8-group lg = (wk half)*4 + kv4-block&3;
                    // 8B half within group = kv bit 4. Then XOR lg by d&7.
                    const int s6 = srow & 63;
                    const int lg = ((s6 >> 5) << 2) | ((s6 >> 2) & 3);
                    const int half = (s6 >> 4) & 1;
                    const int pos =
                        (srow & ~63) + ((lg ^ (hd & 7)) << 3) + (half << 2);
                    *reinterpret_cast<uint2*>(&vout[(size_t)hd * SEQ_LEN + pos]) =
                        make_uint2(p0, p1);
                }
            }
        }
    }
}

// ---------------------------------------------------------------------------
// MFMA causal flash attention, no-max softmax, ALL staging via DMA.
// SWAPPED QK^T: S^T = mfma(K, Q) puts lane l15 = q, rows = kv, so the
// exp2'd tile IS the PV A-fragment under the kv-permutation psi that the
// producer bakes into V^T. P never touches LDS (no transpose, no spill).
// Q arrives pre-scaled by QSCL, so softmax is exp2-only; the diagonal tile
// is PEELED out of the main loop so 32/33 tiles compile mask-free.
// Block = 64 q-rows x 1 head (512 blocks). LPT pairing: first 256 dispatched
// blocks take qt=31..16 (heavy), second 256 take qt=0..15 -> each CU's block
// pair sums to exactly 33 kv-tiles.
// 4 waves = 2(q-half of 32) x 2(kv-half of 32); K/V^T double-buffered, one
// barrier per kv-tile, DMA prefetch right after barrier. Epilogue combines
// the two kv-half waves via LDS overlay. LDS 40 KB.
// ---------------------------------------------------------------------------
__global__ __launch_bounds__(256) void attn_mfma(const u16* __restrict__ Qb,
                                                 const u16* __restrict__ Kb,
                                                 const u16* __restrict__ Vg,
                                                 u16* __restrict__ O) {
    __shared__ u16 SM[4096 + 8192 + 8192];  // 40960 B
    u16* Qs = SM;                // [64 q][64 d]
    u16* Ks = SM + 4096;         // [2 buf][64 kv][64 d], d-groups ^ (s&7)
    u16* Vs = SM + 4096 + 8192;  // [2 buf][64 d][64 kv], psi + groups ^ (d&7)
    // epilogue overlays (main-loop LDS dead by then):
    float* OredF = (float*)SM;           // [64 q][68] fp32 (17408 B)
    float* Lr = (float*)(SM + 8704);     // [2 wk][64 q] fp32 (512 B @ 17408)

    const int b = blockIdx.x;
    const int hb = b >> 4;
    // LPT pairing: CU gets blocks b and b+256 -> qt pair (31-hb, hb) sums 33
    const int qt = (hb < 16) ? (31 - hb) : (hb - 16);
    const int h = b & 15;
    const int q0 = qt * 64;

    const int t = threadIdx.x;
    const int lane = t & 63;
    const int quad = lane >> 4;
    const int l15 = lane & 15;
    const int w = t >> 6;
    const int wq = w >> 1;  // q half (32 rows)
    const int wk = w & 1;   // kv half (32 cols)

    const int drow = t >> 3;       // DMA: row within 32-row group
    const int doff = (t & 7) * 8;  // DMA: 16B lane offset (u16 units)

    auto stageK = [&](int buf, int j0) {
#pragma unroll
        for (int c = 0; c < 2; ++c)
            load_lds16(Kb + (size_t)(j0 + c * 32 + drow) * DIM + h * DHEAD + doff,
                       &Ks[buf * 4096 + c * 2048 + t * 8]);
    };
    auto stageV = [&](int buf, int j0) {
#pragma unroll
        for (int c = 0; c < 2; ++c)
            load_lds16(Vg + (size_t)(h * DHEAD + c * 32 + drow) * SEQ_LEN + j0 + doff,
                       &Vs[buf * 4096 + c * 2048 + t * 8]);
    };

    // ---- prologue: stage Q, K0, V0 ----
#pragma unroll
    for (int c = 0; c < 2; ++c)
        load_lds16(Qb + (size_t)(q0 + c * 32 + drow) * DIM + h * DHEAD + doff,
                   &Qs[c * 2048 + t * 8]);
    stageK(0, 0);
    stageV(0, 0);
    __syncthreads();  // all prologue DMA drained

    // Q as B-fragment: lane l15 = q, quad = d-group (same map as A-fragment)
    bf16x8 qf[2][2];
#pragma unroll
    for (int qq = 0; qq < 2; ++qq)
#pragma unroll
        for (int dc = 0; dc < 2; ++dc)
            qf[qq][dc] = *reinterpret_cast<const bf16x8*>(
                &Qs[(wq * 32 + qq * 16 + l15) * 64 + dc * 32 + quad * 8]);

    f32x4 oacc[2][4] = {};
    float lsum[2] = {};

    // ---- main loop: non-diagonal tiles (mask-free softmax) ----
    for (int jt = 0; jt < qt; ++jt) {
        const int cur = jt & 1, nxt = cur ^ 1;
        if (jt > 0) __syncthreads();  // buf[cur] DMA drained; buf[nxt] readers done
        stageK(nxt, (jt + 1) * 64);   // prefetch next tile (jt+1 <= qt always)
        stageV(nxt, (jt + 1) * 64);

        // S^T = K @ Q^T (wave: 32 kv x 32 q), lane l15 = q
        f32x4 sacc[2][2] = {};  // [qq][nn kv-tile]
#pragma unroll
        for (int nn = 0; nn < 2; ++nn)
#pragma unroll
            for (int dc = 0; dc < 2; ++dc) {
                const bf16x8 kf = *reinterpret_cast<const bf16x8*>(
                    &Ks[cur * 4096 + (wk * 32 + nn * 16 + l15) * 64 +
                        (((dc * 4 + quad) ^ (l15 & 7)) << 3)]);
#pragma unroll
                for (int qq = 0; qq < 2; ++qq)
                    sacc[qq][nn] =
                        __builtin_amdgcn_mfma_f32_16x16x32_bf16(kf, qf[qq][dc], sacc[qq][nn], 0, 0, 0);
            }

        // exp2-only softmax, fully in-register (S pre-scaled via Q)
        bf16x8 pfr[2];
#pragma unroll
        for (int qq = 0; qq < 2; ++qq)
#pragma unroll
            for (int nn = 0; nn < 2; ++nn)
#pragma unroll
                for (int r = 0; r < 4; ++r) {
                    const float p = exp2f(sacc[qq][nn][r]);
                    lsum[qq] += p;
                    pfr[qq][nn * 4 + r] = (short)(__float_as_uint(p) >> 16);
                }

        // O += P @ V (wave's 32-kv slice of V^T; psi-matched)
#pragma unroll
        for (int nd = 0; nd < 4; ++nd) {
            const bf16x8 vf = *reinterpret_cast<const bf16x8*>(
                &Vs[cur * 4096 + (nd * 16 + l15) * 64 +
                    (((wk * 4 + quad) ^ (l15 & 7)) << 3)]);
#pragma unroll
            for (int qq = 0; qq < 2; ++qq)
                oacc[qq][nd] =
                    __builtin_amdgcn_mfma_f32_16x16x32_bf16(pfr[qq], vf, oacc[qq][nd], 0, 0, 0);
        }
    }

    // ---- peeled diagonal tile (jt = qt): causal mask active ----
    {
        const int cur = qt & 1;
        if (qt > 0) __syncthreads();  // buf[cur] DMA drained

        f32x4 sacc[2][2] = {};
#pragma unroll
        for (int nn = 0; nn < 2; ++nn)
#pragma unroll
            for (int dc = 0; dc < 2; ++dc) {
                const bf16x8 kf = *reinterpret_cast<const bf16x8*>(
                    &Ks[cur * 4096 + (wk * 32 + nn * 16 + l15) * 64 +
                        (((dc * 4 + quad) ^ (l15 & 7)) << 3)]);
#pragma unroll
                for (int qq = 0; qq < 2; ++qq)
                    sacc[qq][nn] =
                        __builtin_amdgcn_mfma_f32_16x16x32_bf16(kf, qf[qq][dc], sacc[qq][nn], 0, 0, 0);
            }

        bf16x8 pfr[2];
#pragma unroll
        for (int qq = 0; qq < 2; ++qq) {
            const int qrow = wq * 32 + qq * 16 + l15;
#pragma unroll
            for (int nn = 0; nn < 2; ++nn)
#pragma unroll
                for (int r = 0; r < 4; ++r) {
                    float p = sacc[qq][nn][r];
                    if (wk * 32 + nn * 16 + quad * 4 + r > qrow) p = -1e30f;
                    p = exp2f(p);
                    lsum[qq] += p;
                    pfr[qq][nn * 4 + r] = (short)(__float_as_uint(p) >> 16);
                }
        }

#pragma unroll
        for (int nd = 0; nd < 4; ++nd) {
            const bf16x8 vf = *reinterpret_cast<const bf16x8*>(
                &Vs[cur * 4096 + (nd * 16 + l15) * 64 +
                    (((wk * 4 + quad) ^ (l15 & 7)) << 3)]);
#pragma unroll
            for (int qq = 0; qq < 2; ++qq)
                oacc[qq][nd] =
                    __builtin_amdgcn_mfma_f32_16x16x32_bf16(pfr[qq], vf, oacc[qq][nd], 0, 0, 0);
        }
    }

    // ---- epilogue ----
    // lsum lives per-lane at q = l15 (per qq); reduce over quad lanes.
#pragma unroll
    for (int qq = 0; qq < 2; ++qq) {
        lsum[qq] += __shfl_xor(lsum[qq], 16, 64);
        lsum[qq] += __shfl_xor(lsum[qq], 32, 64);
    }
    __syncthreads();  // main-loop LDS dead; overlays safe
    if (quad == 0) {  // publish per-row l partials (both kv halves)
#pragma unroll
        for (int qq = 0; qq < 2; ++qq)
            Lr[wk * 64 + wq * 32 + qq * 16 + l15] = lsum[qq];
    }
    // wk=1 waves publish their kv-half O partials to LDS
    if (wk == 1) {
#pragma unroll
        for (int qq = 0; qq < 2; ++qq)
#pragma unroll
            for (int r = 0; r < 4; ++r) {
                const int rowl = wq * 32 + qq * 16 + quad * 4 + r;
#pragma unroll
                for (int nd = 0; nd < 4; ++nd)
                    OredF[rowl * 68 + nd * 16 + l15] = oacc[qq][nd][r];
            }
    }
    __syncthreads();
    // wk=0 waves combine, normalize (combined l > 0 always), write bf16
    if (wk == 0) {
#pragma unroll
        for (int qq = 0; qq < 2; ++qq)
#pragma unroll
            for (int r = 0; r < 4; ++r) {
                const int rowl = wq * 32 + qq * 16 + quad * 4 + r;
                const float inv = 1.0f / (Lr[rowl] + Lr[64 + rowl]);
                const int row = q0 + rowl;
#pragma unroll
                for (int nd = 0; nd < 4; ++nd)
                    O[(size_t)row * DIM + h * DHEAD + nd * 16 + l15] =
                        f2bf((oacc[qq][nd][r] + OredF[rowl * 68 + nd * 16 + l15]) * inv);
            }
    }
}

// ---------------------------------------------------------------------------
extern "C" void kernel_launch(void* const* d_in, const int* in_sizes, int n_in,
                              void* d_out, int out_size, void* d_ws, size_t ws_size,
                              hipStream_t stream) {
    const float* x = (const float*)d_in[0];     // [2048,1024]
    const float* Wqkv = (const float*)d_in[1];  // [1024,3072]
    const float* Wout = (const float*)d_in[2];  // [1024,1024]
    const float* bias = (const float*)d_in[3];  // [1024]
    float* out = (float*)d_out;

    char* ws = (char*)d_ws;
    u16* xb = (u16*)ws;                     // 4 MB
    u16* Wqkvt = (u16*)(ws + (4u << 20));   // 6 MB  [3072,1024]
    u16* Woutt = (u16*)(ws + (10u << 20));  // 2 MB  [1024,1024]
    u16* Qb = (u16*)(ws + (12u << 20));     // 4 MB  [2048,1024] pre-scaled
    u16* Kb = (u16*)(ws + (16u << 20));     // 4 MB  [2048,1024] swizzled
    u16* Vg = (u16*)(ws + (20u << 20));     // 4 MB  [1024,2048] V^T psi+swz
    u16* Ob = (u16*)(ws + (24u << 20));     // 4 MB  [2048,1024]

    // fused prep: cast x + transpose Wqkv + transpose Wout (64x64 vectorized)
    prep_k<<<dim3(3072), 256, 0, stream>>>(x, Wqkv, Wout, xb, Wqkvt, Woutt);

    // qkv = x @ Wqkv, split-layout epilogue (Q-prescaled / K-swz / V^T-psi)
    // 128x64xBK=64: 768 blocks = 3/CU exactly (grid balance beats tile size
    // here -- 128x128 gave 384 blocks = 1.5 rounds, measured neutral/worse)
    gemm_bf16<0, 128, 64, 64><<<dim3(QKV_LD / 64, SEQ_LEN / 128), 256, 0, stream>>>(
        xb, Wqkvt, nullptr, Qb, Kb, Vg, SEQ_LEN, QKV_LD, DIM);

    // causal attention: 512 blocks, LPT-paired (each CU pair sums 33 tiles)
    attn_mfma<<<dim3(32 * NHEAD), 256, 0, stream>>>(Qb, Kb, Vg, Ob);

    // out = O @ Wout + bias (fp32): 64x64x64 tiles -> 512 blocks
    gemm_bf16<1, 64, 64, 64><<<dim3(DIM / 64, SEQ_LEN / 64), 256, 0, stream>>>(
        Ob, Woutt, bias, out, nullptr, nullptr, SEQ_LEN, DIM, DIM);
}